// Round 12
// baseline (240.214 us; speedup 1.0000x reference)
//
#include <hip/hip_runtime.h>
#include <hip/hip_bf16.h>

#define NDIM 256
#define NN (NDIM*NDIM)

typedef __attribute__((ext_vector_type(8))) short s8bf;     // 8 x bf16 (4 VGPRs)
typedef __attribute__((ext_vector_type(4))) float f32x4;    // native float4
typedef __attribute__((ext_vector_type(16))) float f32x16;  // 32x32 MFMA accum

__device__ __forceinline__ unsigned short f2bf(float f) {
    union { float f; unsigned u; } v; v.f = f;
    unsigned u = v.u;
    return (unsigned short)((u + 0x7FFFu + ((u >> 16) & 1u)) >> 16);  // RNE
}
__device__ __forceinline__ short f2bfs(float f) {           // compiler emits v_cvt_pk_bf16_f32
    __hip_bfloat16 h = __float2bfloat16(f);
    union { __hip_bfloat16 h; short s; } v; v.h = h;
    return v.s;
}

// ---------------- expm pipeline: U = B0 + M3*(B1 + M3/720) ----------------
// M = H1 - i*H0. deg-6 Taylor; truncation ~1e-4 << bf16 noise.
__global__ __launch_bounds__(1024) void kmm(
    const float* __restrict__ H, float2* __restrict__ M2c, float2* __restrict__ M3c,
    unsigned short* __restrict__ Ut, int mode) {
    __shared__ float2 As[16][257];
    __shared__ float2 Bs[256][17];
    __shared__ float2 Rs[3][16][17];
    const int tx = threadIdx.x, ty = threadIdx.y, tz = threadIdx.z;
    const int tid = (tz * 16 + ty) * 16 + tx;
    const int r0 = blockIdx.y * 16, c0 = blockIdx.x * 16;

#pragma unroll
    for (int i = 0; i < 4; ++i) {               // A panel: 16 rows x 256 k
        int idx = i * 1024 + tid;
        int r = idx >> 8, k = idx & 255;
        float2 a;
        if (mode == 0)      { a.x = H[NN + (r0+r)*NDIM + k]; a.y = -H[(r0+r)*NDIM + k]; }
        else if (mode == 1) a = M2c[(r0+r)*NDIM + k];
        else                a = M3c[(r0+r)*NDIM + k];
        As[r][k] = a;
    }
#pragma unroll
    for (int i = 0; i < 4; ++i) {               // B panel: 256 k x 16 cols
        int idx = i * 1024 + tid;
        int k = idx >> 4, cc = idx & 15;
        float2 b;
        if (mode <= 1) { b.x = H[NN + k*NDIM + c0+cc]; b.y = -H[k*NDIM + c0+cc]; }
        else {
            int g = k * NDIM + c0 + cc;
            float mr = H[NN + g], mi = -H[g];
            float2 m2 = M2c[g], m3 = M3c[g];
            float di = (k == c0 + cc) ? 1.f : 0.f;
            b.x = di*(1.f/6.f) + mr*(1.f/24.f) + m2.x*(1.f/120.f) + m3.x*(1.f/720.f);
            b.y =                mi*(1.f/24.f) + m2.y*(1.f/120.f) + m3.y*(1.f/720.f);
        }
        Bs[k][cc] = b;
    }
    __syncthreads();

    float sr0=0.f, si0=0.f, sr1=0.f, si1=0.f;
#pragma unroll 8
    for (int k = tz*64; k < tz*64 + 64; k += 2) {
        float2 a = As[ty][k], b = Bs[k][tx];
        sr0 = fmaf(a.x, b.x, sr0); sr0 = fmaf(-a.y, b.y, sr0);
        si0 = fmaf(a.x, b.y, si0); si0 = fmaf(a.y, b.x, si0);
        float2 a1 = As[ty][k+1], b1 = Bs[k+1][tx];
        sr1 = fmaf(a1.x, b1.x, sr1); sr1 = fmaf(-a1.y, b1.y, sr1);
        si1 = fmaf(a1.x, b1.y, si1); si1 = fmaf(a1.y, b1.x, si1);
    }
    float sr = sr0 + sr1, si = si0 + si1;
    if (tz > 0) Rs[tz-1][ty][tx] = make_float2(sr, si);
    __syncthreads();
    if (tz == 0) {
        sr += Rs[0][ty][tx].x + Rs[1][ty][tx].x + Rs[2][ty][tx].x;
        si += Rs[0][ty][tx].y + Rs[1][ty][tx].y + Rs[2][ty][tx].y;
        int d = r0 + ty, e = c0 + tx;
        if (mode == 0)      M2c[d*NDIM + e] = make_float2(sr, si);
        else if (mode == 1) M3c[d*NDIM + e] = make_float2(sr, si);
        else {
            int g = d * NDIM + e;
            float ur = sr + ((d == e) ? 1.f : 0.f) + H[NN + g] + M2c[g].x * 0.5f;
            Ut[e * NDIM + d] = f2bf(ur);         // transposed: Ut[col][k]
        }
    }
}

// ---------------- main GEMM: out[131072 x 256] = psi @ Re(U) ----------------
// "minimal-32": every previously-identified serializer removed at once.
//  - B = FULL Ut in 128 KB XOR-swizzled LDS, staged once (psi read ONCE,
//    no R10 col-split duplication); ONE __syncthreads total.
//  - A = depth-3 register ring (R10-proven: no spill, VGPR_Count 64).
//  - mfma_32x32x16, acc[4] f32x16 (AGPRs): C stored DIRECTLY, each 4B/lane
//    NT store = 2 full 128B lines -> no epilogue, no transpose, no RMW.
//  - No per-slice barriers (R11's cadence), no sched_barriers.
// 1024 thr = 16 waves = 8 rowgroups x 2 colhalves; 2 strips of 256 rows;
// grid 256 = 1 block/CU.
__global__ __launch_bounds__(1024, 4) void kgemm(
    const float* __restrict__ psi, const unsigned short* __restrict__ Ut,
    float* __restrict__ out) {
    __shared__ unsigned short Bls[NN];          // 128 KB, swizzled 16B slots
    const int t = threadIdx.x;

    // stage Ut -> LDS: 16B chunk (cl, j) at (cl<<5)|(j^(cl&7))
    const s8bf* Ug = (const s8bf*)Ut;
    s8bf* Bg = (s8bf*)Bls;
#pragma unroll
    for (int i = 0; i < 8; ++i) {
        int g = i * 1024 + t;                   // [0, 8192)
        int cl = g >> 5, j = g & 31;
        Bg[(cl << 5) | (j ^ (cl & 7))] = Ug[g];
    }
    __syncthreads();                            // the kernel's only barrier

    const int w = t >> 6, l = t & 63;
    const int lr = l & 31, half = l >> 5;
    const int rg = w >> 1, ch = w & 1;
    const f32x4* psi4 = (const f32x4*)psi;

#pragma unroll 1
    for (int strip = 0; strip < 2; ++strip) {
        const size_t rowb = (size_t)blockIdx.x * 512 + strip * 256 + rg * 32;
        const size_t abase = (rowb + lr) * 64 + half * 2;   // f32x4 units

        f32x4 Ar[3][2];                          // depth-3 k-step ring
#pragma unroll
        for (int p = 0; p < 3; ++p) {
            Ar[p][0] = psi4[abase + p * 4];
            Ar[p][1] = psi4[abase + p * 4 + 1];
        }

        f32x16 acc[4];
#pragma unroll
        for (int p = 0; p < 4; ++p) acc[p] = (f32x16)0.f;

#pragma unroll
        for (int ks = 0; ks < 16; ++ks) {
            s8bf a;                              // A: row=lr, k=ks*16+half*8+j
#pragma unroll
            for (int j = 0; j < 4; ++j) {
                a[j]     = f2bfs(Ar[ks % 3][0][j]);
                a[j + 4] = f2bfs(Ar[ks % 3][1][j]);
            }
            if (ks + 3 < 16) {                   // refill ring slot for ks+3
                Ar[ks % 3][0] = psi4[abase + (ks + 3) * 4];
                Ar[ks % 3][1] = psi4[abase + (ks + 3) * 4 + 1];
            }
            const int jp = 2 * ks + half;        // B chunk slot in col
#pragma unroll
            for (int p = 0; p < 4; ++p) {        // 4 col-panels of 32
                int cl = ch * 128 + p * 32 + lr;
                s8bf bb = Bg[(cl << 5) | (jp ^ (cl & 7))];
                acc[p] = __builtin_amdgcn_mfma_f32_32x32x16_bf16(a, bb, acc[p], 0, 0, 0);
            }
        }

        // direct C stores: col=lane&31, row=(r&3)+8*(r>>2)+4*half [R10-verified]
#pragma unroll
        for (int p = 0; p < 4; ++p) {
#pragma unroll
            for (int r = 0; r < 16; ++r) {
                size_t row = rowb + (r & 3) + 8 * (r >> 2) + 4 * half;
                __builtin_nontemporal_store(acc[p][r],
                    &out[row * NDIM + ch * 128 + p * 32 + lr]);
            }
        }
    }
}

extern "C" void kernel_launch(void* const* d_in, const int* in_sizes, int n_in,
                              void* d_out, int out_size, void* d_ws, size_t ws_size,
                              hipStream_t stream) {
    const float* psi = (const float*)d_in[0];   // [8,4096,4,256] f32
    const float* H   = (const float*)d_in[1];   // [4,256,256]    f32
    float* out = (float*)d_out;                 // [8,4096,4,256] f32

    float2* M2c = (float2*)d_ws;                // NN complex
    float2* M3c = M2c + NN;                     // NN complex
    unsigned short* Ut = (unsigned short*)(M3c + NN);  // NN bf16 (Ut[col][k])

    dim3 cb(16, 16, 4), cg(16, 16);
    kmm<<<cg, cb, 0, stream>>>(H, M2c, M3c, Ut, 0);   // M2 = M*M
    kmm<<<cg, cb, 0, stream>>>(H, M2c, M3c, Ut, 1);   // M3 = M2*M
    kmm<<<cg, cb, 0, stream>>>(H, M2c, M3c, Ut, 2);   // Ut = bf16(Re(U))^T
    kgemm<<<256, 1024, 0, stream>>>(psi, Ut, out);
}

// Round 13
// 96.501 us; speedup vs baseline: 2.4892x; 2.4892x over previous
//
#include <hip/hip_runtime.h>
#include <hip/hip_bf16.h>

#define NDIM 256
#define NN (NDIM*NDIM)

typedef __attribute__((ext_vector_type(8))) short s8bf;    // 8 x bf16 (4 VGPRs)
typedef __attribute__((ext_vector_type(4))) float f32x4;   // MFMA accum / native float4

__device__ __forceinline__ unsigned short f2bf(float f) {
    union { float f; unsigned u; } v; v.f = f;
    unsigned u = v.u;
    return (unsigned short)((u + 0x7FFFu + ((u >> 16) & 1u)) >> 16);  // RNE
}
__device__ __forceinline__ short f2bfs(float f) {          // compiler emits v_cvt_pk_bf16_f32
    __hip_bfloat16 h = __float2bfloat16(f);
    union { __hip_bfloat16 h; short s; } v; v.h = h;
    return v.s;
}

// ---------------- expm pipeline: U = B0 + M3*(B1 + M3/720) ----------------
// M = H1 - i*H0. deg-6 Taylor; truncation ~1e-4 << bf16 noise.
// 1024 thr (16,16,4): K split 4 ways across tz + 2-way sub-accumulators.
__global__ __launch_bounds__(1024) void kmm(
    const float* __restrict__ H, float2* __restrict__ M2c, float2* __restrict__ M3c,
    unsigned short* __restrict__ Ut, int mode) {
    __shared__ float2 As[16][257];
    __shared__ float2 Bs[256][17];
    __shared__ float2 Rs[3][16][17];
    const int tx = threadIdx.x, ty = threadIdx.y, tz = threadIdx.z;
    const int tid = (tz * 16 + ty) * 16 + tx;
    const int r0 = blockIdx.y * 16, c0 = blockIdx.x * 16;

#pragma unroll
    for (int i = 0; i < 4; ++i) {               // A panel: 16 rows x 256 k
        int idx = i * 1024 + tid;
        int r = idx >> 8, k = idx & 255;
        float2 a;
        if (mode == 0)      { a.x = H[NN + (r0+r)*NDIM + k]; a.y = -H[(r0+r)*NDIM + k]; }
        else if (mode == 1) a = M2c[(r0+r)*NDIM + k];
        else                a = M3c[(r0+r)*NDIM + k];
        As[r][k] = a;
    }
#pragma unroll
    for (int i = 0; i < 4; ++i) {               // B panel: 256 k x 16 cols
        int idx = i * 1024 + tid;
        int k = idx >> 4, cc = idx & 15;
        float2 b;
        if (mode <= 1) { b.x = H[NN + k*NDIM + c0+cc]; b.y = -H[k*NDIM + c0+cc]; }
        else {
            int g = k * NDIM + c0 + cc;
            float mr = H[NN + g], mi = -H[g];
            float2 m2 = M2c[g], m3 = M3c[g];
            float di = (k == c0 + cc) ? 1.f : 0.f;
            b.x = di*(1.f/6.f) + mr*(1.f/24.f) + m2.x*(1.f/120.f) + m3.x*(1.f/720.f);
            b.y =                mi*(1.f/24.f) + m2.y*(1.f/120.f) + m3.y*(1.f/720.f);
        }
        Bs[k][cc] = b;
    }
    __syncthreads();

    float sr0=0.f, si0=0.f, sr1=0.f, si1=0.f;
#pragma unroll 8
    for (int k = tz*64; k < tz*64 + 64; k += 2) {
        float2 a = As[ty][k], b = Bs[k][tx];
        sr0 = fmaf(a.x, b.x, sr0); sr0 = fmaf(-a.y, b.y, sr0);
        si0 = fmaf(a.x, b.y, si0); si0 = fmaf(a.y, b.x, si0);
        float2 a1 = As[ty][k+1], b1 = Bs[k+1][tx];
        sr1 = fmaf(a1.x, b1.x, sr1); sr1 = fmaf(-a1.y, b1.y, sr1);
        si1 = fmaf(a1.x, b1.y, si1); si1 = fmaf(a1.y, b1.x, si1);
    }
    float sr = sr0 + sr1, si = si0 + si1;
    if (tz > 0) Rs[tz-1][ty][tx] = make_float2(sr, si);
    __syncthreads();
    if (tz == 0) {
        sr += Rs[0][ty][tx].x + Rs[1][ty][tx].x + Rs[2][ty][tx].x;
        si += Rs[0][ty][tx].y + Rs[1][ty][tx].y + Rs[2][ty][tx].y;
        int d = r0 + ty, e = c0 + tx;
        if (mode == 0)      M2c[d*NDIM + e] = make_float2(sr, si);
        else if (mode == 1) M3c[d*NDIM + e] = make_float2(sr, si);
        else {
            int g = d * NDIM + e;
            float ur = sr + ((d == e) ? 1.f : 0.f) + H[NN + g] + M2c[g].x * 0.5f;
            Ut[e * NDIM + d] = f2bf(ur);         // transposed: Ut[col][k]
        }
    }
}

// ---------------- main GEMM: out[131072 x 256] = psi @ Re(U) ----------------
// R6-proven structure (72.2 us total, best known): 1024 thr = 16 waves x 16
// rows; B = full Ut in 128 KB XOR-swizzled LDS; psi read FULL-LINE (16 rows x
// 128B per instr — the invariant every fast round shares); depth-2 ring;
// ping-pong 1-row LDS epilogue -> 1 KB NT stores. Single change vs R6: strip
// 0's initial prefetch is issued BEFORE __syncthreads (overlaps B-stage
// drain; global+reg only, no LDS interaction).
__global__ __launch_bounds__(1024, 4) void kgemm(
    const float* __restrict__ psi, const unsigned short* __restrict__ Ut,
    float* __restrict__ out) {
    __shared__ unsigned short Bls[NN];          // 128 KB, swizzled 16B slots
    __shared__ float Escr[16][512];             // 32 KB: 2 KB/wave (2 x 1 KB halves)
    const int t = threadIdx.x;

    // stage Ut -> LDS: slot(r,j) = r*32 + (j ^ (r&7)), 16B units
    const s8bf* Ug = (const s8bf*)Ut;
    s8bf* Bg = (s8bf*)Bls;
#pragma unroll
    for (int i = 0; i < 8; ++i) {
        int g = i * 1024 + t;                   // 16B-chunk id in [0, 8192)
        int r = g >> 5, j = g & 31;
        Bg[(r << 5) | (j ^ (r & 7))] = Ug[g];
    }

    const int w = t >> 6, lane = t & 63;
    const int c = lane & 15, q = lane >> 4;
    const f32x4* psi4 = (const f32x4*)psi;
    f32x4* out4 = (f32x4*)out;
    float* Ebase = &Escr[w][0];

    // strip-0 prefetch issued BEFORE the barrier (hidden under B-stage drain)
    const size_t rl0 = ((size_t)blockIdx.x * 512 + w * 16 + c) * 64;
    f32x4 pb[2][2];                              // depth-2 prefetch ring
    pb[0][0] = psi4[rl0 + q*2];     pb[0][1] = psi4[rl0 + q*2 + 1];
    pb[1][0] = psi4[rl0 + 8 + q*2]; pb[1][1] = psi4[rl0 + 8 + q*2 + 1];

    __syncthreads();

#pragma unroll 1
    for (int st = 0; st < 2; ++st) {
        const int base = blockIdx.x * 512 + st * 256 + w * 16;
        const size_t rl = (size_t)(base + c) * 64;     // f32x4 units

        f32x4 acc[16];
#pragma unroll
        for (int i = 0; i < 16; ++i) acc[i] = (f32x4)0.f;

        if (st > 0) {                            // re-init ring for this strip
            pb[0][0] = psi4[rl + q*2];     pb[0][1] = psi4[rl + q*2 + 1];
            pb[1][0] = psi4[rl + 8 + q*2]; pb[1][1] = psi4[rl + 8 + q*2 + 1];
        }

#pragma unroll
        for (int s = 0; s < 8; ++s) {
            s8bf a;
#pragma unroll
            for (int j = 0; j < 4; ++j) {
                a[j]     = f2bfs(pb[s & 1][0][j]);
                a[j + 4] = f2bfs(pb[s & 1][1][j]);
            }
            if (s < 6) {                         // refill slot for step s+2
                int o = (s + 2) * 8 + q * 2;
                pb[s & 1][0] = psi4[rl + o];
                pb[s & 1][1] = psi4[rl + o + 1];
            }
#pragma unroll
            for (int ct = 0; ct < 16; ++ct) {
                int rr = ct * 16 + c;
                s8bf bb = Bg[(rr << 5) | ((s*4 + q) ^ (rr & 7))];
                acc[ct] = __builtin_amdgcn_mfma_f32_16x16x32_bf16(a, bb, acc[ct], 0, 0, 0);
            }
        }

        // epilogue: 16 passes x 1 row, ping-pong 1 KB halves, full-line stores
#pragma unroll
        for (int p = 0; p < 16; ++p) {
            const int qq = p >> 2, rr = p & 3;
            float* E = Ebase + (p & 1) * 256;
            if (q == qq) {
#pragma unroll
                for (int ct = 0; ct < 16; ++ct)
                    E[ct * 16 + c] = acc[ct][rr];
            }
            f32x4 vv = *(const f32x4*)(&E[lane * 4]);
            __builtin_nontemporal_store(vv, &out4[(size_t)(base + p) * 64 + lane]);
            __builtin_amdgcn_sched_barrier(0);   // pin pass ordering (WAR safety)
        }
    }
}

extern "C" void kernel_launch(void* const* d_in, const int* in_sizes, int n_in,
                              void* d_out, int out_size, void* d_ws, size_t ws_size,
                              hipStream_t stream) {
    const float* psi = (const float*)d_in[0];   // [8,4096,4,256] f32
    const float* H   = (const float*)d_in[1];   // [4,256,256]    f32
    float* out = (float*)d_out;                 // [8,4096,4,256] f32

    float2* M2c = (float2*)d_ws;                // NN complex
    float2* M3c = M2c + NN;                     // NN complex
    unsigned short* Ut = (unsigned short*)(M3c + NN);  // NN bf16 (Ut[col][k])

    dim3 cb(16, 16, 4), cg(16, 16);
    kmm<<<cg, cb, 0, stream>>>(H, M2c, M3c, Ut, 0);   // M2 = M*M
    kmm<<<cg, cb, 0, stream>>>(H, M2c, M3c, Ut, 1);   // M3 = M2*M
    kmm<<<cg, cb, 0, stream>>>(H, M2c, M3c, Ut, 2);   // Ut = bf16(Re(U))^T
    kgemm<<<256, 1024, 0, stream>>>(psi, Ut, out);
}

// Round 14
// 71.550 us; speedup vs baseline: 3.3573x; 1.3487x over previous
//
#include <hip/hip_runtime.h>
#include <hip/hip_bf16.h>

#define NDIM 256
#define NN (NDIM*NDIM)

typedef __attribute__((ext_vector_type(8))) short s8bf;    // 8 x bf16 (4 VGPRs)
typedef __attribute__((ext_vector_type(4))) float f32x4;   // MFMA accum / native float4

__device__ __forceinline__ unsigned short f2bf(float f) {
    union { float f; unsigned u; } v; v.f = f;
    unsigned u = v.u;
    return (unsigned short)((u + 0x7FFFu + ((u >> 16) & 1u)) >> 16);  // RNE
}
__device__ __forceinline__ short f2bfs(float f) {          // compiler emits v_cvt_pk_bf16_f32
    __hip_bfloat16 h = __float2bfloat16(f);
    union { __hip_bfloat16 h; short s; } v; v.h = h;
    return v.s;
}

// ---------------- expm pipeline: U = B0 + M3*(B1 + M3/720) ----------------
// M = H1 - i*H0. deg-6 Taylor; truncation ~1e-4 << bf16 noise.
// 1024 thr (16,16,4): K split 4 ways across tz + 2-way sub-accumulators.
__global__ __launch_bounds__(1024) void kmm(
    const float* __restrict__ H, float2* __restrict__ M2c, float2* __restrict__ M3c,
    unsigned short* __restrict__ Ut, int mode) {
    __shared__ float2 As[16][257];
    __shared__ float2 Bs[256][17];
    __shared__ float2 Rs[3][16][17];
    const int tx = threadIdx.x, ty = threadIdx.y, tz = threadIdx.z;
    const int tid = (tz * 16 + ty) * 16 + tx;
    const int r0 = blockIdx.y * 16, c0 = blockIdx.x * 16;

#pragma unroll
    for (int i = 0; i < 4; ++i) {               // A panel: 16 rows x 256 k
        int idx = i * 1024 + tid;
        int r = idx >> 8, k = idx & 255;
        float2 a;
        if (mode == 0)      { a.x = H[NN + (r0+r)*NDIM + k]; a.y = -H[(r0+r)*NDIM + k]; }
        else if (mode == 1) a = M2c[(r0+r)*NDIM + k];
        else                a = M3c[(r0+r)*NDIM + k];
        As[r][k] = a;
    }
#pragma unroll
    for (int i = 0; i < 4; ++i) {               // B panel: 256 k x 16 cols
        int idx = i * 1024 + tid;
        int k = idx >> 4, cc = idx & 15;
        float2 b;
        if (mode <= 1) { b.x = H[NN + k*NDIM + c0+cc]; b.y = -H[k*NDIM + c0+cc]; }
        else {
            int g = k * NDIM + c0 + cc;
            float mr = H[NN + g], mi = -H[g];
            float2 m2 = M2c[g], m3 = M3c[g];
            float di = (k == c0 + cc) ? 1.f : 0.f;
            b.x = di*(1.f/6.f) + mr*(1.f/24.f) + m2.x*(1.f/120.f) + m3.x*(1.f/720.f);
            b.y =                mi*(1.f/24.f) + m2.y*(1.f/120.f) + m3.y*(1.f/720.f);
        }
        Bs[k][cc] = b;
    }
    __syncthreads();

    float sr0=0.f, si0=0.f, sr1=0.f, si1=0.f;
#pragma unroll 8
    for (int k = tz*64; k < tz*64 + 64; k += 2) {
        float2 a = As[ty][k], b = Bs[k][tx];
        sr0 = fmaf(a.x, b.x, sr0); sr0 = fmaf(-a.y, b.y, sr0);
        si0 = fmaf(a.x, b.y, si0); si0 = fmaf(a.y, b.x, si0);
        float2 a1 = As[ty][k+1], b1 = Bs[k+1][tx];
        sr1 = fmaf(a1.x, b1.x, sr1); sr1 = fmaf(-a1.y, b1.y, sr1);
        si1 = fmaf(a1.x, b1.y, si1); si1 = fmaf(a1.y, b1.x, si1);
    }
    float sr = sr0 + sr1, si = si0 + si1;
    if (tz > 0) Rs[tz-1][ty][tx] = make_float2(sr, si);
    __syncthreads();
    if (tz == 0) {
        sr += Rs[0][ty][tx].x + Rs[1][ty][tx].x + Rs[2][ty][tx].x;
        si += Rs[0][ty][tx].y + Rs[1][ty][tx].y + Rs[2][ty][tx].y;
        int d = r0 + ty, e = c0 + tx;
        if (mode == 0)      M2c[d*NDIM + e] = make_float2(sr, si);
        else if (mode == 1) M3c[d*NDIM + e] = make_float2(sr, si);
        else {
            int g = d * NDIM + e;
            float ur = sr + ((d == e) ? 1.f : 0.f) + H[NN + g] + M2c[g].x * 0.5f;
            Ut[e * NDIM + d] = f2bf(ur);         // transposed: Ut[col][k]
        }
    }
}

// ---------------- main GEMM: out[131072 x 256] = psi @ Re(U) ----------------
// BYTE-EXACT round-6 kernel (72.2 us total — best of 13 rounds; every
// deviation tried since either tied or regressed). 1024 thr = 16 waves x 16
// rows (acc[16] = 64 VGPR; launch_bounds caps 128 VGPR -> 16 waves/CU).
// B (Ut, 128 KB bf16) staged once per block, XOR-swizzled. psi streamed with
// depth-2 prefetch, full-line-per-instruction-pair reads. Epilogue: 1-row
// passes ping-ponged between two 1 KB halves (distance-2 reuse only) ->
// full-line 1 KB NT stores. LDS = 160 KiB exact.
__global__ __launch_bounds__(1024, 4) void kgemm(
    const float* __restrict__ psi, const unsigned short* __restrict__ Ut,
    float* __restrict__ out) {
    __shared__ unsigned short Bls[NN];          // 128 KB, swizzled 16B slots
    __shared__ float Escr[16][512];             // 32 KB: 2 KB/wave (2 x 1 KB halves)
    const int t = threadIdx.x;

    // stage Ut -> LDS: slot(r,j) = r*32 + (j ^ (r&7)), 16B units
    const s8bf* Ug = (const s8bf*)Ut;
    s8bf* Bg = (s8bf*)Bls;
#pragma unroll
    for (int i = 0; i < 8; ++i) {
        int g = i * 1024 + t;                   // 16B-chunk id in [0, 8192)
        int r = g >> 5, j = g & 31;
        Bg[(r << 5) | (j ^ (r & 7))] = Ug[g];
    }
    __syncthreads();

    const int w = t >> 6, lane = t & 63;
    const int c = lane & 15, q = lane >> 4;
    const f32x4* psi4 = (const f32x4*)psi;
    f32x4* out4 = (f32x4*)out;
    float* Ebase = &Escr[w][0];

#pragma unroll 1
    for (int st = 0; st < 2; ++st) {
        const int base = blockIdx.x * 512 + st * 256 + w * 16;
        const size_t rl = (size_t)(base + c) * 64;     // f32x4 units

        f32x4 acc[16];
#pragma unroll
        for (int i = 0; i < 16; ++i) acc[i] = (f32x4)0.f;

        f32x4 pb[2][2];                          // depth-2 prefetch ring
        pb[0][0] = psi4[rl + q*2];     pb[0][1] = psi4[rl + q*2 + 1];
        pb[1][0] = psi4[rl + 8 + q*2]; pb[1][1] = psi4[rl + 8 + q*2 + 1];

#pragma unroll
        for (int s = 0; s < 8; ++s) {
            s8bf a;
#pragma unroll
            for (int j = 0; j < 4; ++j) {
                a[j]     = f2bfs(pb[s & 1][0][j]);
                a[j + 4] = f2bfs(pb[s & 1][1][j]);
            }
            if (s < 6) {                         // refill slot for step s+2
                int o = (s + 2) * 8 + q * 2;
                pb[s & 1][0] = psi4[rl + o];
                pb[s & 1][1] = psi4[rl + o + 1];
            }
#pragma unroll
            for (int ct = 0; ct < 16; ++ct) {
                int rr = ct * 16 + c;
                s8bf bb = Bg[(rr << 5) | ((s*4 + q) ^ (rr & 7))];
                acc[ct] = __builtin_amdgcn_mfma_f32_16x16x32_bf16(a, bb, acc[ct], 0, 0, 0);
            }
        }

        // epilogue: 16 passes x 1 row, ping-pong 1 KB halves, full-line stores
#pragma unroll
        for (int p = 0; p < 16; ++p) {
            const int qq = p >> 2, rr = p & 3;
            float* E = Ebase + (p & 1) * 256;
            if (q == qq) {
#pragma unroll
                for (int ct = 0; ct < 16; ++ct)
                    E[ct * 16 + c] = acc[ct][rr];
            }
            f32x4 vv = *(const f32x4*)(&E[lane * 4]);
            __builtin_nontemporal_store(vv, &out4[(size_t)(base + p) * 64 + lane]);
            __builtin_amdgcn_sched_barrier(0);   // pin pass ordering (WAR safety)
        }
    }
}

extern "C" void kernel_launch(void* const* d_in, const int* in_sizes, int n_in,
                              void* d_out, int out_size, void* d_ws, size_t ws_size,
                              hipStream_t stream) {
    const float* psi = (const float*)d_in[0];   // [8,4096,4,256] f32
    const float* H   = (const float*)d_in[1];   // [4,256,256]    f32
    float* out = (float*)d_out;                 // [8,4096,4,256] f32

    float2* M2c = (float2*)d_ws;                // NN complex
    float2* M3c = M2c + NN;                     // NN complex
    unsigned short* Ut = (unsigned short*)(M3c + NN);  // NN bf16 (Ut[col][k])

    dim3 cb(16, 16, 4), cg(16, 16);
    kmm<<<cg, cb, 0, stream>>>(H, M2c, M3c, Ut, 0);   // M2 = M*M
    kmm<<<cg, cb, 0, stream>>>(H, M2c, M3c, Ut, 1);   // M3 = M2*M
    kmm<<<cg, cb, 0, stream>>>(H, M2c, M3c, Ut, 2);   // Ut = bf16(Re(U))^T
    kgemm<<<256, 1024, 0, stream>>>(psi, Ut, out);
}